// Round 1
// 95.633 us; speedup vs baseline: 1.0236x; 1.0236x over previous
//
#include <hip/hip_runtime.h>

typedef _Float16 half8 __attribute__((ext_vector_type(8)));
typedef float f32x4 __attribute__((ext_vector_type(4)));

#define NN 4096
#define NE 512
#define HD 64
#define KROWS 4288   // 64 pad + 4096 + 128 pad (per batch)
#define KOFF  64
#define WSCALE (1.0f / 256.0f)

// --- f16 helpers: RN hi + RN residual lo; hi+lo == f to ~2^-23 rel ---
__device__ __forceinline__ void f16_split(float f, _Float16& hi, _Float16& lo) {
    hi = (_Float16)f;                    // v_cvt_f16_f32 (round-to-nearest)
    lo = (_Float16)(f - (float)hi);
}

#define MFMA16(a, b, c) __builtin_amdgcn_mfma_f32_16x16x32_f16((a), (b), (c), 0, 0, 0)

// ---------------------------------------------------------------------------
// wprep: (a) W=[Wq|Wk|Wv] (512x192) -> B-frag order, f16 RN.
//        (b) zero K pad rows + Vs (pads are load-bearing: pad keys pass the
//            j-validity check and must contribute exp(0)-1 = 0).
//        (c) Vf init: zeros + f16 ones plane nt=4.
// ---------------------------------------------------------------------------
__global__ __launch_bounds__(256) void wprep_kernel(
    const float* __restrict__ Wq, const float* __restrict__ Wk,
    const float* __restrict__ Wv,
    _Float16* __restrict__ Wf, _Float16* __restrict__ Khi,
    _Float16* __restrict__ Vf, float* __restrict__ Vs)
{
    const int gtid = blockIdx.x * 256 + threadIdx.x;   // [0, 12288)
    const int L = gtid & 63;
    {
        const int nt = (gtid >> 6) % 12;
        const int kt = gtid / 768;
        const int n = nt * 16 + (L & 15);
        const int kbase = kt * 32 + (L >> 4) * 8;
        const float* src; int col;
        if (n < 64)       { src = Wq; col = n; }
        else if (n < 128) { src = Wk; col = n - 64; }
        else              { src = Wv; col = n - 128; }
        half8 sh;
#pragma unroll
        for (int j = 0; j < 8; ++j)
            sh[j] = (_Float16)src[(size_t)(kbase + j) * HD + col];
        *(half8*)(Wf + (size_t)gtid * 8) = sh;
    }
    if (gtid < 6144) {   // zero 768 pad rows x 128 B
        const int p = gtid >> 3, o = gtid & 7;
        const int b = p / 192, q = p - b * 192;
        const size_t row = (size_t)b * KROWS + (q < 64 ? q : 4096 + q);
        const half8 z = {0, 0, 0, 0, 0, 0, 0, 0};
        *(half8*)(Khi + row * HD + o * 8) = z;
    }
    if (gtid < 3200) {   // Vf init: zeros; nt==4 plane gets ones-pattern
        const int rem = gtid % 1600;
        const int jt = rem / 320;
        const int nt = (rem / 64) % 5;
        half8 sh = {0, 0, 0, 0, 0, 0, 0, 0};
        if (nt == 4 && (L & 15) == 0) {
#pragma unroll
            for (int jj = 0; jj < 8; ++jj) {
                const int j = jt * 32 + (L >> 4) * 8 + jj;
                if (j < 129) sh[jj] = (_Float16)1.0f;
            }
        }
        *(half8*)(Vf + (size_t)gtid * 8) = sh;
    }
    if (gtid < 128) Vs[gtid] = 0.f;
}

// ---------------------------------------------------------------------------
// proj: QKV = x @ W + b, 2-pass f16 MFMA ((xhi + xlo) * Whi-RN).
// ROUND-9 CHANGE: 256 blocks x 1024 threads, 32 rows/block (was 512x512,
// 16 rows). Same 4096 waves = 16/CU TLP, but Wf L2 traffic halves
// (100 MB -> 50 MB) and mt-paired waves (same t3,h slice) hit L1.
// Wave = mtile (w>>3) x nt-triple ((w>>1)&3) x k-half (w&1).
// V-frag emission simplifies: block local=jt covers exactly jt's 32 rows.
// ---------------------------------------------------------------------------
__global__ __launch_bounds__(1024, 4) void proj_kernel(
    const float* __restrict__ x, const _Float16* __restrict__ Wf,
    const float* __restrict__ bq, const float* __restrict__ bk,
    const float* __restrict__ bv,
    _Float16* __restrict__ Qhi, _Float16* __restrict__ Qlo,
    _Float16* __restrict__ Khi, _Float16* __restrict__ Vf,
    float* __restrict__ Vs)
{
    __shared__ float parts[2][4][3][64][4];   // k-half-1 partials (24 KB)
    __shared__ float V_lds[32][68];
    const int tid = threadIdx.x;
    const int L = tid & 63;
    const int w = tid >> 6;              // wave 0..15
    const int m = L & 15, kg = L >> 4;
    const int blk = blockIdx.x;          // 0..255
    const int b = blk >> 7;
    const int mt = w >> 3;               // row sub-tile 0/1
    const int t3 = (w >> 1) & 3;         // nt-triple: nts 3*t3..3*t3+2
    const int h = w & 1;                 // k-half: kts 8h..8h+7
    const int r0 = blk * 32;             // global row base (spans batches)
    const int rr = r0 + mt * 16;

    const float* xp = x + (size_t)(rr + m) * NE + h * 256 + kg * 8;
    const _Float16* wfb = Wf + ((size_t)(h * 8) * 12 + t3 * 3) * 512 + L * 8;

    f32x4 acc[3];
#pragma unroll
    for (int t = 0; t < 3; ++t) acc[t] = (f32x4){0.f, 0.f, 0.f, 0.f};

#pragma unroll
    for (int kt = 0; kt < 8; ++kt) {
        const float4 x0 = *(const float4*)(xp + kt * 32);
        const float4 x1 = *(const float4*)(xp + kt * 32 + 4);
        const float xv[8] = {x0.x, x0.y, x0.z, x0.w, x1.x, x1.y, x1.z, x1.w};
        half8 ahi, alo;
#pragma unroll
        for (int j = 0; j < 8; ++j) {
            _Float16 hh, ll; f16_split(xv[j], hh, ll);
            ahi[j] = hh; alo[j] = ll;
        }
#pragma unroll
        for (int t = 0; t < 3; ++t) {
            const half8 wv = *(const half8*)(wfb + (size_t)kt * 6144 + t * 512);
            acc[t] = MFMA16(ahi, wv, acc[t]);
            acc[t] = MFMA16(alo, wv, acc[t]);
        }
    }

    if (h == 1) {
#pragma unroll
        for (int t = 0; t < 3; ++t)
            *(f32x4*)(&parts[mt][t3][t][L][0]) = acc[t];
    }
    __syncthreads();

    if (h == 0) {
#pragma unroll
        for (int t = 0; t < 3; ++t) {
            const f32x4 p = *(const f32x4*)(&parts[mt][t3][t][L][0]);
            acc[t] += p;
            const int nt = t3 * 3 + t;
            const int cgc = nt * 16 + m;     // global col 0..191
            const float bias = (cgc < 64) ? bq[cgc]
                             : (cgc < 128) ? bk[cgc - 64] : bv[cgc - 128];
#pragma unroll
            for (int r = 0; r < 4; ++r) {
                const int gr = rr + kg * 4 + r;
                const float val = acc[t][r] + bias;
                if (cgc < 64) {
                    _Float16 hh, ll; f16_split(val, hh, ll);
                    Qhi[(size_t)gr * HD + cgc] = hh;
                    Qlo[(size_t)gr * HD + cgc] = ll;
                } else if (cgc < 128) {
                    const int d = cgc - 64, n = gr & 4095;
                    Khi[((size_t)b * KROWS + KOFF + n) * HD + d] = (_Float16)val;
                } else {
                    V_lds[mt * 16 + kg * 4 + r][cgc - 128] = val;
                }
            }
        }
    }
    __syncthreads();

    // Vsum: one atomic per dim (32 local rows)
    if (tid < 64) {
        float s = 0.f;
#pragma unroll
        for (int r = 0; r < 32; ++r) s += V_lds[r][tid];
        atomicAdd(&Vs[b * HD + tid], s);
    }

    // V-frag emission: block local==jt (<4) owns exactly jt's 32 rows;
    // block local==4 owns j==128 (its local row 0).
    {
        const int local = blk & 127;
        if (local < 4 && w < 4) {
            const int jt = local;
            const int nt = w;                 // V ntile 0..3
            half8 sh;
#pragma unroll
            for (int jj = 0; jj < 8; ++jj)
                sh[jj] = (_Float16)V_lds[kg * 8 + jj][nt * 16 + m];
            const size_t fo = ((size_t)((b * 25 + jt * 5 + nt) * 64 + L)) * 8;
            *(half8*)(Vf + fo) = sh;
        } else if (local == 4 && w < 4 && kg == 0) {
            const int nt = w;
            half8 sh = {0, 0, 0, 0, 0, 0, 0, 0};
            sh[0] = (_Float16)V_lds[0][nt * 16 + m];   // j == 128
            const size_t fo = ((size_t)((b * 25 + 4 * 5 + nt) * 64 + L)) * 8;
            *(half8*)(Vf + fo) = sh;
        }
    }
}

// ---------------------------------------------------------------------------
// attn: grid 512 (b = blk>>8, 16 queries/block), block 256 (4 waves).
// ROUND-9 CHANGES: (1) Vs load hoisted into the upfront batch (was a
// dependent ~200-900cy hop after the last barrier). (2) wt zero-fill
// shrunk to the j in [129,168) strip only — phase 1 provably writes every
// (q, j<129) since l=q+j<=143 is covered by ktiles 0..8 — and since the
// strip is disjoint from phase-1 writes, the pre-phase-1 barrier is gone.
// ---------------------------------------------------------------------------
__global__ __launch_bounds__(256) void attn_kernel(
    const _Float16* __restrict__ Qhi, const _Float16* __restrict__ Qlo,
    const _Float16* __restrict__ Khi, const _Float16* __restrict__ Vf,
    const float* __restrict__ Vs, float* __restrict__ out)
{
    __shared__ __align__(16) _Float16 wt_hi[16 * 168];
    __shared__ __align__(16) _Float16 wt_lo[16 * 168];
    __shared__ float den_lds[16];

    const int tid = threadIdx.x;
    const int L = tid & 63;
    const int w = tid >> 6;
    const int m = L & 15, kg = L >> 4;
    const int b = blockIdx.x >> 8;
    const int n0 = (blockIdx.x & 255) * 16;

    // ---- upfront load issuance (all independent) ----
    const float vs = Vs[b * HD + w * 16 + m];          // epilogue const

    const _Float16* qp  = Qhi + ((size_t)(b * NN + n0 + m)) * HD + kg * 8;
    const _Float16* qp2 = Qlo + ((size_t)(b * NN + n0 + m)) * HD + kg * 8;
    const half8 qhi0 = *(const half8*)(qp);
    const half8 qhi1 = *(const half8*)(qp + 32);
    const half8 qlo0 = *(const half8*)(qp2);
    const half8 qlo1 = *(const half8*)(qp2 + 32);

    int kts[3]; int nkt;
    if (w == 3) { kts[0] = 3; kts[1] = 7; kts[2] = 8; nkt = 3; }
    else        { kts[0] = w; kts[1] = w + 4; kts[2] = 0; nkt = 2; }

    const _Float16* KB = Khi + (size_t)b * KROWS * HD;
    half8 kh0[3], kh1[3];
#pragma unroll
    for (int i = 0; i < 3; ++i) {
        if (i < nkt) {                   // wave-uniform branch
            const _Float16* kp = KB + (size_t)(n0 + kts[i] * 16 + m) * HD + kg * 8;
            kh0[i] = *(const half8*)(kp);
            kh1[i] = *(const half8*)(kp + 32);
        }
    }

    half8 vhi[5], vh4[5];
#pragma unroll
    for (int jt = 0; jt < 5; ++jt) {
        const size_t fo = ((size_t)((b * 25 + jt * 5 + w) * 64 + L)) * 8;
        vhi[jt] = *(const half8*)(Vf + fo);
    }
    if (w == 0) {                        // wave-uniform
#pragma unroll
        for (int jt = 0; jt < 5; ++jt) {
            const size_t fo4 = ((size_t)((b * 25 + jt * 5 + 4) * 64 + L)) * 8;
            vh4[jt] = *(const half8*)(Vf + fo4);
        }
    }

    // zero only the j in [129,168) strip (39 cols x 16 q, both buffers).
    // Disjoint from phase-1 writes (j < 129) -> no barrier needed here.
    for (int t = tid; t < 1248; t += 256) {
        const int bufsel = t >= 624;
        const int idx = bufsel ? t - 624 : t;
        const int q = idx / 39;
        const int j = 129 + (idx - q * 39);
        (bufsel ? wt_lo : wt_hi)[q * 168 + j] = (_Float16)0.f;
    }

    // ---- phase 1 ----
#pragma unroll
    for (int i = 0; i < 3; ++i) {
        if (i < nkt) {
            f32x4 acc = (f32x4){0.f, 0.f, 0.f, 0.f};
            acc = MFMA16(qhi0, kh0[i], acc);
            acc = MFMA16(qhi1, kh1[i], acc);
            acc = MFMA16(qlo0, kh0[i], acc);
            acc = MFMA16(qlo1, kh1[i], acc);
            const int l = kts[i] * 16 + m;
#pragma unroll
            for (int r = 0; r < 4; ++r) {
                const int q = kg * 4 + r;
                const int j = l - q;
                if (j >= 0 && j < 129) {
                    const float wval = (__expf(acc[r]) - 1.0f) * WSCALE;
                    _Float16 hh, ll; f16_split(wval, hh, ll);
                    wt_hi[q * 168 + j] = hh;
                    wt_lo[q * 168 + j] = ll;
                }
            }
        }
    }
    __syncthreads();

    // ---- phase 2 ----
    f32x4 oacc = (f32x4){0.f, 0.f, 0.f, 0.f};
    f32x4 dacc = (f32x4){0.f, 0.f, 0.f, 0.f};
#pragma unroll
    for (int jt = 0; jt < 5; ++jt) {
        const half8 whi = *(const half8*)(wt_hi + m * 168 + jt * 32 + kg * 8);
        const half8 wlo = *(const half8*)(wt_lo + m * 168 + jt * 32 + kg * 8);
        oacc = MFMA16(whi, vhi[jt], oacc);
        oacc = MFMA16(wlo, vhi[jt], oacc);
        if (w == 0) {
            dacc = MFMA16(whi, vh4[jt], dacc);
            dacc = MFMA16(wlo, vh4[jt], dacc);
        }
    }
    if (w == 0 && m == 0) {
#pragma unroll
        for (int r = 0; r < 4; ++r) den_lds[kg * 4 + r] = dacc[r];
    }
    __syncthreads();

    // ---- epilogue (unscale: num = 256*oacc, den = 4096 + 256*dacc) ----
    {
#pragma unroll
        for (int r = 0; r < 4; ++r) {
            const int q = kg * 4 + r;
            const float val = (vs + 256.0f * oacc[r])
                            / (4096.f + 256.0f * den_lds[q]);
            out[((size_t)(b * NN + n0 + q)) * HD + w * 16 + m] = val;
        }
    }
}

// ---------------------------------------------------------------------------
extern "C" void kernel_launch(void* const* d_in, const int* in_sizes, int n_in,
                              void* d_out, int out_size, void* d_ws, size_t ws_size,
                              hipStream_t stream)
{
    const float* x  = (const float*)d_in[0];
    const float* Wq = (const float*)d_in[1];
    const float* bq = (const float*)d_in[2];
    const float* Wk = (const float*)d_in[3];
    const float* bk = (const float*)d_in[4];
    const float* Wv = (const float*)d_in[5];
    const float* bv = (const float*)d_in[6];
    float* out = (float*)d_out;

    char* ws = (char*)d_ws;
    float*     Vs  = (float*)(ws + 0);              //      512 B
    _Float16*  Khi = (_Float16*)(ws + 512);         // 1097728 B
    _Float16*  Qhi = (_Float16*)(ws + 1098240);     // 1048576 B
    _Float16*  Qlo = (_Float16*)(ws + 2146816);     // 1048576 B
    _Float16*  Wf  = (_Float16*)(ws + 3195392);     //  196608 B
    _Float16*  Vf  = (_Float16*)(ws + 3392000);     //   51200 B

    wprep_kernel<<<48, 256, 0, stream>>>(Wq, Wk, Wv, Wf, Khi, Vf, Vs);
    proj_kernel<<<256, 1024, 0, stream>>>(x, Wf, bq, bk, bv,
                                          Qhi, Qlo, Khi, Vf, Vs);
    attn_kernel<<<512, 256, 0, stream>>>(Qhi, Qlo, Khi, Vf, Vs, out);
}

// Round 2
// 94.761 us; speedup vs baseline: 1.0330x; 1.0092x over previous
//
#include <hip/hip_runtime.h>

typedef _Float16 half8 __attribute__((ext_vector_type(8)));
typedef float f32x4 __attribute__((ext_vector_type(4)));

#define NN 4096
#define NE 512
#define HD 64
#define KROWS 4288   // 64 pad + 4096 + 128 pad (per batch)
#define KOFF  64
#define WSCALE (1.0f / 256.0f)

// --- f16 helpers: RN hi + RN residual lo; hi+lo == f to ~2^-23 rel ---
__device__ __forceinline__ void f16_split(float f, _Float16& hi, _Float16& lo) {
    hi = (_Float16)f;                    // v_cvt_f16_f32 (round-to-nearest)
    lo = (_Float16)(f - (float)hi);
}

#define MFMA16(a, b, c) __builtin_amdgcn_mfma_f32_16x16x32_f16((a), (b), (c), 0, 0, 0)

// ---------------------------------------------------------------------------
// wprep: (a) W=[Wq|Wk|Wv] (512x192) -> B-frag order, f16 RN.
//        (b) zero K pad rows + Vs (pads are load-bearing: pad keys pass the
//            j-validity check and must contribute exp(0)-1 = 0).
//        (c) Vf init: zeros + f16 ones plane nt=4.
// ROUND-10: 192 blocks x 64 threads (was 48 x 256) — same gtid mapping,
// 4x CU coverage for the latency-bound scattered W gather at the head of
// the pipeline.
// ---------------------------------------------------------------------------
__global__ __launch_bounds__(64) void wprep_kernel(
    const float* __restrict__ Wq, const float* __restrict__ Wk,
    const float* __restrict__ Wv,
    _Float16* __restrict__ Wf, _Float16* __restrict__ Khi,
    _Float16* __restrict__ Vf, float* __restrict__ Vs)
{
    const int gtid = blockIdx.x * 64 + threadIdx.x;    // [0, 12288)
    const int L = gtid & 63;
    {
        const int nt = (gtid >> 6) % 12;
        const int kt = gtid / 768;
        const int n = nt * 16 + (L & 15);
        const int kbase = kt * 32 + (L >> 4) * 8;
        const float* src; int col;
        if (n < 64)       { src = Wq; col = n; }
        else if (n < 128) { src = Wk; col = n - 64; }
        else              { src = Wv; col = n - 128; }
        half8 sh;
#pragma unroll
        for (int j = 0; j < 8; ++j)
            sh[j] = (_Float16)src[(size_t)(kbase + j) * HD + col];
        *(half8*)(Wf + (size_t)gtid * 8) = sh;
    }
    if (gtid < 6144) {   // zero 768 pad rows x 128 B
        const int p = gtid >> 3, o = gtid & 7;
        const int b = p / 192, q = p - b * 192;
        const size_t row = (size_t)b * KROWS + (q < 64 ? q : 4096 + q);
        const half8 z = {0, 0, 0, 0, 0, 0, 0, 0};
        *(half8*)(Khi + row * HD + o * 8) = z;
    }
    if (gtid < 3200) {   // Vf init: zeros; nt==4 plane gets ones-pattern
        const int rem = gtid % 1600;
        const int jt = rem / 320;
        const int nt = (rem / 64) % 5;
        half8 sh = {0, 0, 0, 0, 0, 0, 0, 0};
        if (nt == 4 && (L & 15) == 0) {
#pragma unroll
            for (int jj = 0; jj < 8; ++jj) {
                const int j = jt * 32 + (L >> 4) * 8 + jj;
                if (j < 129) sh[jj] = (_Float16)1.0f;
            }
        }
        *(half8*)(Vf + (size_t)gtid * 8) = sh;
    }
    if (gtid < 128) Vs[gtid] = 0.f;
}

// ---------------------------------------------------------------------------
// proj: QKV = x @ W + b, 2-pass f16 MFMA ((xhi + xlo) * Whi-RN).
// 256 blocks x 1024 threads, 32 rows/block. 4096 waves = 16/CU TLP.
// Wave = mtile (w>>3) x nt-triple ((w>>1)&3) x k-half (w&1).
// (unchanged from round 9 — TLP structure proven rounds 5/7/8/9)
// ---------------------------------------------------------------------------
__global__ __launch_bounds__(1024, 4) void proj_kernel(
    const float* __restrict__ x, const _Float16* __restrict__ Wf,
    const float* __restrict__ bq, const float* __restrict__ bk,
    const float* __restrict__ bv,
    _Float16* __restrict__ Qhi, _Float16* __restrict__ Qlo,
    _Float16* __restrict__ Khi, _Float16* __restrict__ Vf,
    float* __restrict__ Vs)
{
    __shared__ float parts[2][4][3][64][4];   // k-half-1 partials (24 KB)
    __shared__ float V_lds[32][68];
    const int tid = threadIdx.x;
    const int L = tid & 63;
    const int w = tid >> 6;              // wave 0..15
    const int m = L & 15, kg = L >> 4;
    const int blk = blockIdx.x;          // 0..255
    const int b = blk >> 7;
    const int mt = w >> 3;               // row sub-tile 0/1
    const int t3 = (w >> 1) & 3;         // nt-triple: nts 3*t3..3*t3+2
    const int h = w & 1;                 // k-half: kts 8h..8h+7
    const int r0 = blk * 32;             // global row base (spans batches)
    const int rr = r0 + mt * 16;

    const float* xp = x + (size_t)(rr + m) * NE + h * 256 + kg * 8;
    const _Float16* wfb = Wf + ((size_t)(h * 8) * 12 + t3 * 3) * 512 + L * 8;

    f32x4 acc[3];
#pragma unroll
    for (int t = 0; t < 3; ++t) acc[t] = (f32x4){0.f, 0.f, 0.f, 0.f};

#pragma unroll
    for (int kt = 0; kt < 8; ++kt) {
        const float4 x0 = *(const float4*)(xp + kt * 32);
        const float4 x1 = *(const float4*)(xp + kt * 32 + 4);
        const float xv[8] = {x0.x, x0.y, x0.z, x0.w, x1.x, x1.y, x1.z, x1.w};
        half8 ahi, alo;
#pragma unroll
        for (int j = 0; j < 8; ++j) {
            _Float16 hh, ll; f16_split(xv[j], hh, ll);
            ahi[j] = hh; alo[j] = ll;
        }
#pragma unroll
        for (int t = 0; t < 3; ++t) {
            const half8 wv = *(const half8*)(wfb + (size_t)kt * 6144 + t * 512);
            acc[t] = MFMA16(ahi, wv, acc[t]);
            acc[t] = MFMA16(alo, wv, acc[t]);
        }
    }

    if (h == 1) {
#pragma unroll
        for (int t = 0; t < 3; ++t)
            *(f32x4*)(&parts[mt][t3][t][L][0]) = acc[t];
    }
    __syncthreads();

    if (h == 0) {
#pragma unroll
        for (int t = 0; t < 3; ++t) {
            const f32x4 p = *(const f32x4*)(&parts[mt][t3][t][L][0]);
            acc[t] += p;
            const int nt = t3 * 3 + t;
            const int cgc = nt * 16 + m;     // global col 0..191
            const float bias = (cgc < 64) ? bq[cgc]
                             : (cgc < 128) ? bk[cgc - 64] : bv[cgc - 128];
#pragma unroll
            for (int r = 0; r < 4; ++r) {
                const int gr = rr + kg * 4 + r;
                const float val = acc[t][r] + bias;
                if (cgc < 64) {
                    _Float16 hh, ll; f16_split(val, hh, ll);
                    Qhi[(size_t)gr * HD + cgc] = hh;
                    Qlo[(size_t)gr * HD + cgc] = ll;
                } else if (cgc < 128) {
                    const int d = cgc - 64, n = gr & 4095;
                    Khi[((size_t)b * KROWS + KOFF + n) * HD + d] = (_Float16)val;
                } else {
                    V_lds[mt * 16 + kg * 4 + r][cgc - 128] = val;
                }
            }
        }
    }
    __syncthreads();

    // Vsum: one atomic per dim (32 local rows)
    if (tid < 64) {
        float s = 0.f;
#pragma unroll
        for (int r = 0; r < 32; ++r) s += V_lds[r][tid];
        atomicAdd(&Vs[b * HD + tid], s);
    }

    // V-frag emission: block local==jt (<4) owns exactly jt's 32 rows;
    // block local==4 owns j==128 (its local row 0).
    {
        const int local = blk & 127;
        if (local < 4 && w < 4) {
            const int jt = local;
            const int nt = w;                 // V ntile 0..3
            half8 sh;
#pragma unroll
            for (int jj = 0; jj < 8; ++jj)
                sh[jj] = (_Float16)V_lds[kg * 8 + jj][nt * 16 + m];
            const size_t fo = ((size_t)((b * 25 + jt * 5 + nt) * 64 + L)) * 8;
            *(half8*)(Vf + fo) = sh;
        } else if (local == 4 && w < 4 && kg == 0) {
            const int nt = w;
            half8 sh = {0, 0, 0, 0, 0, 0, 0, 0};
            sh[0] = (_Float16)V_lds[0][nt * 16 + m];   // j == 128
            const size_t fo = ((size_t)((b * 25 + 4 * 5 + nt) * 64 + L)) * 8;
            *(half8*)(Vf + fo) = sh;
        }
    }
}

// ---------------------------------------------------------------------------
// attn ROUND-10: 32 queries/block. grid 256 (b = blk>>7), block 512
// (8 waves). K-tile loads drop 18 -> 10 per 32 q (each interior K tile
// shared by both q-halves) and all block-fixed costs halve.
// Phase 1: S-band = 18 (qt,kt) tiles; wave parity = qt (even w: qt0, odd:
// qt1). 3-tile waves w4/w5 are disjoint from den waves w0/w6 (max 28
// MFMAs/wave vs 32 naive). Phase 2: wave = (mt = w>>2) x (nt = w&3);
// w0/w6 additionally compute den (ones-plane MFMA) for mt 0/1.
// ---------------------------------------------------------------------------
__global__ __launch_bounds__(512) void attn_kernel(
    const _Float16* __restrict__ Qhi, const _Float16* __restrict__ Qlo,
    const _Float16* __restrict__ Khi, const _Float16* __restrict__ Vf,
    const float* __restrict__ Vs, float* __restrict__ out)
{
    __shared__ __align__(16) _Float16 wt_hi[32 * 168];
    __shared__ __align__(16) _Float16 wt_lo[32 * 168];
    __shared__ float den_lds[32];

    const int tid = threadIdx.x;
    const int L = tid & 63;
    const int w = tid >> 6;              // 0..7
    const int m = L & 15, kg = L >> 4;
    const int b = blockIdx.x >> 7;
    const int n0 = (blockIdx.x & 127) * 32;
    const int qt = w & 1;                // phase-1 q-half
    const int mt = w >> 2;               // phase-2 output q-half
    const int nt = w & 3;                // phase-2 output dim tile
    const bool den_wave = (w == 0) || (w == 6);   // mt 0 / 1, both 2-tile

    // ---- upfront load issuance (all independent) ----
    const float vs = Vs[b * HD + nt * 16 + m];         // epilogue const

    const _Float16* qp  = Qhi + ((size_t)(b * NN + n0 + qt * 16 + m)) * HD + kg * 8;
    const _Float16* qp2 = Qlo + ((size_t)(b * NN + n0 + qt * 16 + m)) * HD + kg * 8;
    const half8 qhi0 = *(const half8*)(qp);
    const half8 qhi1 = *(const half8*)(qp + 32);
    const half8 qlo0 = *(const half8*)(qp2);
    const half8 qlo1 = *(const half8*)(qp2 + 32);

    // tile table: even w (qt0) covers kt {0..8}, odd w (qt1) kt {1..9}.
    // i = w>>1: f = {1,2,0,3}[i]; kts = f+qt, f+qt+4, (i==2: f+qt+8).
    const int i4 = w >> 1;
    const int f = (i4 == 0) ? 1 : (i4 == 1) ? 2 : (i4 == 2) ? 0 : 3;
    int kts[3]; int nkt;
    kts[0] = f + qt; kts[1] = f + qt + 4; kts[2] = f + qt + 8;
    nkt = (i4 == 2) ? 3 : 2;

    const _Float16* KB = Khi + (size_t)b * KROWS * HD;
    half8 kh0[3], kh1[3];
#pragma unroll
    for (int i = 0; i < 3; ++i) {
        if (i < nkt) {                   // wave-uniform branch
            const _Float16* kp = KB + (size_t)(n0 + kts[i] * 16 + m) * HD + kg * 8;
            kh0[i] = *(const half8*)(kp);
            kh1[i] = *(const half8*)(kp + 32);
        }
    }

    half8 vhi[5], vh4[5];
#pragma unroll
    for (int jt = 0; jt < 5; ++jt) {
        const size_t fo = ((size_t)((b * 25 + jt * 5 + nt) * 64 + L)) * 8;
        vhi[jt] = *(const half8*)(Vf + fo);
    }
    if (den_wave) {                      // wave-uniform
#pragma unroll
        for (int jt = 0; jt < 5; ++jt) {
            const size_t fo4 = ((size_t)((b * 25 + jt * 5 + 4) * 64 + L)) * 8;
            vh4[jt] = *(const half8*)(Vf + fo4);
        }
    }

    // zero only the j in [129,161) strip (cols >=160 are never read by
    // phase 2; j<129 is fully written by phase 1). Disjoint from phase-1
    // writes -> no barrier needed before phase 1.
    for (int t = tid; t < 2048; t += 512) {
        const int bufsel = t >= 1024;
        const int idx = t & 1023;
        const int q = idx >> 5;
        const int j = 129 + (idx & 31);
        (bufsel ? wt_lo : wt_hi)[q * 168 + j] = (_Float16)0.f;
    }

    // ---- phase 1 ----
#pragma unroll
    for (int i = 0; i < 3; ++i) {
        if (i < nkt) {
            f32x4 acc = (f32x4){0.f, 0.f, 0.f, 0.f};
            acc = MFMA16(qhi0, kh0[i], acc);
            acc = MFMA16(qhi1, kh1[i], acc);
            acc = MFMA16(qlo0, kh0[i], acc);
            acc = MFMA16(qlo1, kh1[i], acc);
            const int l = kts[i] * 16 + m;
#pragma unroll
            for (int r = 0; r < 4; ++r) {
                const int q = qt * 16 + kg * 4 + r;
                const int j = l - q;
                if (j >= 0 && j < 129) {
                    const float wval = (__expf(acc[r]) - 1.0f) * WSCALE;
                    _Float16 hh, ll; f16_split(wval, hh, ll);
                    wt_hi[q * 168 + j] = hh;
                    wt_lo[q * 168 + j] = ll;
                }
            }
        }
    }
    __syncthreads();

    // ---- phase 2 ----
    f32x4 oacc = (f32x4){0.f, 0.f, 0.f, 0.f};
    f32x4 dacc = (f32x4){0.f, 0.f, 0.f, 0.f};
#pragma unroll
    for (int jt = 0; jt < 5; ++jt) {
        const half8 whi = *(const half8*)(wt_hi + (mt * 16 + m) * 168 + jt * 32 + kg * 8);
        const half8 wlo = *(const half8*)(wt_lo + (mt * 16 + m) * 168 + jt * 32 + kg * 8);
        oacc = MFMA16(whi, vhi[jt], oacc);
        oacc = MFMA16(wlo, vhi[jt], oacc);
        if (den_wave) {
            dacc = MFMA16(whi, vh4[jt], dacc);
            dacc = MFMA16(wlo, vh4[jt], dacc);
        }
    }
    if (den_wave && m == 0) {
#pragma unroll
        for (int r = 0; r < 4; ++r) den_lds[mt * 16 + kg * 4 + r] = dacc[r];
    }
    __syncthreads();

    // ---- epilogue (unscale: num = 256*oacc, den = 4096 + 256*den) ----
    {
#pragma unroll
        for (int r = 0; r < 4; ++r) {
            const int q = mt * 16 + kg * 4 + r;
            const float val = (vs + 256.0f * oacc[r])
                            / (4096.f + 256.0f * den_lds[q]);
            out[((size_t)(b * NN + n0 + q)) * HD + nt * 16 + m] = val;
        }
    }
}

// ---------------------------------------------------------------------------
extern "C" void kernel_launch(void* const* d_in, const int* in_sizes, int n_in,
                              void* d_out, int out_size, void* d_ws, size_t ws_size,
                              hipStream_t stream)
{
    const float* x  = (const float*)d_in[0];
    const float* Wq = (const float*)d_in[1];
    const float* bq = (const float*)d_in[2];
    const float* Wk = (const float*)d_in[3];
    const float* bk = (const float*)d_in[4];
    const float* Wv = (const float*)d_in[5];
    const float* bv = (const float*)d_in[6];
    float* out = (float*)d_out;

    char* ws = (char*)d_ws;
    float*     Vs  = (float*)(ws + 0);              //      512 B
    _Float16*  Khi = (_Float16*)(ws + 512);         // 1097728 B
    _Float16*  Qhi = (_Float16*)(ws + 1098240);     // 1048576 B
    _Float16*  Qlo = (_Float16*)(ws + 2146816);     // 1048576 B
    _Float16*  Wf  = (_Float16*)(ws + 3195392);     //  196608 B
    _Float16*  Vf  = (_Float16*)(ws + 3392000);     //   51200 B

    wprep_kernel<<<192, 64, 0, stream>>>(Wq, Wk, Wv, Wf, Khi, Vf, Vs);
    proj_kernel<<<256, 1024, 0, stream>>>(x, Wf, bq, bk, bv,
                                          Qhi, Qlo, Khi, Vf, Vs);
    attn_kernel<<<256, 512, 0, stream>>>(Qhi, Qlo, Khi, Vf, Vs, out);
}

// Round 3
// 94.504 us; speedup vs baseline: 1.0358x; 1.0027x over previous
//
#include <hip/hip_runtime.h>

typedef _Float16 half8 __attribute__((ext_vector_type(8)));
typedef float f32x4 __attribute__((ext_vector_type(4)));

#define NN 4096
#define NE 512
#define HD 64
#define KROWS 4288   // 64 pad + 4096 + 128 pad (per batch)
#define KOFF  64
#define WSCALE (1.0f / 256.0f)

// --- f16 helpers: RN hi + RN residual lo; hi+lo == f to ~2^-23 rel ---
__device__ __forceinline__ void f16_split(float f, _Float16& hi, _Float16& lo) {
    hi = (_Float16)f;                    // v_cvt_f16_f32 (round-to-nearest)
    lo = (_Float16)(f - (float)hi);
}

#define MFMA16(a, b, c) __builtin_amdgcn_mfma_f32_16x16x32_f16((a), (b), (c), 0, 0, 0)

// ---------------------------------------------------------------------------
// wprep: (a) W=[Wq|Wk|Wv] (512x192) -> B-frag order, f16 RN.
//        (b) zero K pad rows + Vs (pads are load-bearing: pad keys pass the
//            j-validity check and must contribute exp(0)-1 = 0).
//        (c) Vf init: zeros + f16 ones plane nt=4.
// 192 blocks x 64 threads — max CU coverage for the latency-bound gather.
// ---------------------------------------------------------------------------
__global__ __launch_bounds__(64) void wprep_kernel(
    const float* __restrict__ Wq, const float* __restrict__ Wk,
    const float* __restrict__ Wv,
    _Float16* __restrict__ Wf, _Float16* __restrict__ Khi,
    _Float16* __restrict__ Vf, float* __restrict__ Vs)
{
    const int gtid = blockIdx.x * 64 + threadIdx.x;    // [0, 12288)
    const int L = gtid & 63;
    {
        const int nt = (gtid >> 6) % 12;
        const int kt = gtid / 768;
        const int n = nt * 16 + (L & 15);
        const int kbase = kt * 32 + (L >> 4) * 8;
        const float* src; int col;
        if (n < 64)       { src = Wq; col = n; }
        else if (n < 128) { src = Wk; col = n - 64; }
        else              { src = Wv; col = n - 128; }
        half8 sh;
#pragma unroll
        for (int j = 0; j < 8; ++j)
            sh[j] = (_Float16)src[(size_t)(kbase + j) * HD + col];
        *(half8*)(Wf + (size_t)gtid * 8) = sh;
    }
    if (gtid < 6144) {   // zero 768 pad rows x 128 B
        const int p = gtid >> 3, o = gtid & 7;
        const int b = p / 192, q = p - b * 192;
        const size_t row = (size_t)b * KROWS + (q < 64 ? q : 4096 + q);
        const half8 z = {0, 0, 0, 0, 0, 0, 0, 0};
        *(half8*)(Khi + row * HD + o * 8) = z;
    }
    if (gtid < 3200) {   // Vf init: zeros; nt==4 plane gets ones-pattern
        const int rem = gtid % 1600;
        const int jt = rem / 320;
        const int nt = (rem / 64) % 5;
        half8 sh = {0, 0, 0, 0, 0, 0, 0, 0};
        if (nt == 4 && (L & 15) == 0) {
#pragma unroll
            for (int jj = 0; jj < 8; ++jj) {
                const int j = jt * 32 + (L >> 4) * 8 + jj;
                if (j < 129) sh[jj] = (_Float16)1.0f;
            }
        }
        *(half8*)(Vf + (size_t)gtid * 8) = sh;
    }
    if (gtid < 128) Vs[gtid] = 0.f;
}

// ---------------------------------------------------------------------------
// proj: QKV = x @ W + b, 2-pass f16 MFMA ((xhi + xlo) * Whi-RN).
// ROUND-11: wave owns BOTH 16-row tiles (acc[2][3], wv reused 4x) and the
// k-axis splits 4-ways (h4, 4 kt each). Wf is now read exactly ONCE per
// block (192 KB) instead of twice — L2 Wf traffic 98 -> 49 MB (proj was
// at the L2 BW ceiling). Same 16 waves/CU TLP, same MFMA count, 2x MFMA
// ILP per wave. 3-partial LDS combine (36 KB).
// Wave = t3 (w&3) x k-quarter (w>>2).
// ---------------------------------------------------------------------------
__global__ __launch_bounds__(1024, 4) void proj_kernel(
    const float* __restrict__ x, const _Float16* __restrict__ Wf,
    const float* __restrict__ bq, const float* __restrict__ bk,
    const float* __restrict__ bv,
    _Float16* __restrict__ Qhi, _Float16* __restrict__ Qlo,
    _Float16* __restrict__ Khi, _Float16* __restrict__ Vf,
    float* __restrict__ Vs)
{
    __shared__ float parts[3][4][2][3][64][4];   // [h4-1][t3][rt][t][lane][4] 36 KB
    __shared__ float V_lds[32][68];
    const int tid = threadIdx.x;
    const int L = tid & 63;
    const int w = tid >> 6;              // wave 0..15
    const int m = L & 15, kg = L >> 4;
    const int blk = blockIdx.x;          // 0..255
    const int b = blk >> 7;
    const int t3 = w & 3;                // nt-triple: nts 3*t3..3*t3+2
    const int h4 = w >> 2;               // k-quarter: kts 4*h4..4*h4+3
    const int r0 = blk * 32;             // global row base (spans batches)

    const float* xp = x + (size_t)(r0 + m) * NE + h4 * 128 + kg * 8;
    const _Float16* wfb = Wf + ((size_t)(h4 * 4) * 12 + t3 * 3) * 512 + L * 8;

    f32x4 acc[2][3];
#pragma unroll
    for (int rt = 0; rt < 2; ++rt)
#pragma unroll
        for (int t = 0; t < 3; ++t) acc[rt][t] = (f32x4){0.f, 0.f, 0.f, 0.f};

#pragma unroll
    for (int kt = 0; kt < 4; ++kt) {
        const float4 a0 = *(const float4*)(xp + kt * 32);
        const float4 a1 = *(const float4*)(xp + kt * 32 + 4);
        const float4 c0 = *(const float4*)(xp + 16 * NE + kt * 32);
        const float4 c1 = *(const float4*)(xp + 16 * NE + kt * 32 + 4);
        const float av[8] = {a0.x, a0.y, a0.z, a0.w, a1.x, a1.y, a1.z, a1.w};
        const float cv[8] = {c0.x, c0.y, c0.z, c0.w, c1.x, c1.y, c1.z, c1.w};
        half8 ahi, alo, chi, clo;
#pragma unroll
        for (int j = 0; j < 8; ++j) {
            _Float16 hh, ll;
            f16_split(av[j], hh, ll); ahi[j] = hh; alo[j] = ll;
            f16_split(cv[j], hh, ll); chi[j] = hh; clo[j] = ll;
        }
#pragma unroll
        for (int t = 0; t < 3; ++t) {
            const half8 wv = *(const half8*)(wfb + (size_t)kt * 6144 + t * 512);
            acc[0][t] = MFMA16(ahi, wv, acc[0][t]);
            acc[0][t] = MFMA16(alo, wv, acc[0][t]);
            acc[1][t] = MFMA16(chi, wv, acc[1][t]);
            acc[1][t] = MFMA16(clo, wv, acc[1][t]);
        }
    }

    if (h4 != 0) {
#pragma unroll
        for (int rt = 0; rt < 2; ++rt)
#pragma unroll
            for (int t = 0; t < 3; ++t)
                *(f32x4*)(&parts[h4 - 1][t3][rt][t][L][0]) = acc[rt][t];
    }
    __syncthreads();

    if (h4 == 0) {
#pragma unroll
        for (int rt = 0; rt < 2; ++rt)
#pragma unroll
        for (int t = 0; t < 3; ++t) {
            f32x4 s = acc[rt][t];
#pragma unroll
            for (int p = 0; p < 3; ++p)
                s += *(const f32x4*)(&parts[p][t3][rt][t][L][0]);
            const int nt = t3 * 3 + t;
            const int cgc = nt * 16 + m;     // global col 0..191
            const float bias = (cgc < 64) ? bq[cgc]
                             : (cgc < 128) ? bk[cgc - 64] : bv[cgc - 128];
#pragma unroll
            for (int r = 0; r < 4; ++r) {
                const int gr = r0 + rt * 16 + kg * 4 + r;
                const float val = s[r] + bias;
                if (cgc < 64) {
                    _Float16 hh, ll; f16_split(val, hh, ll);
                    Qhi[(size_t)gr * HD + cgc] = hh;
                    Qlo[(size_t)gr * HD + cgc] = ll;
                } else if (cgc < 128) {
                    const int d = cgc - 64, n = gr & 4095;
                    Khi[((size_t)b * KROWS + KOFF + n) * HD + d] = (_Float16)val;
                } else {
                    V_lds[rt * 16 + kg * 4 + r][cgc - 128] = val;
                }
            }
        }
    }
    __syncthreads();

    // Vsum: one atomic per dim (32 local rows)
    if (tid < 64) {
        float s = 0.f;
#pragma unroll
        for (int r = 0; r < 32; ++r) s += V_lds[r][tid];
        atomicAdd(&Vs[b * HD + tid], s);
    }

    // V-frag emission: block local==jt (<4) owns exactly jt's 32 rows;
    // block local==4 owns j==128 (its local row 0).
    {
        const int local = blk & 127;
        if (local < 4 && w < 4) {
            const int jt = local;
            const int nt = w;                 // V ntile 0..3
            half8 sh;
#pragma unroll
            for (int jj = 0; jj < 8; ++jj)
                sh[jj] = (_Float16)V_lds[kg * 8 + jj][nt * 16 + m];
            const size_t fo = ((size_t)((b * 25 + jt * 5 + nt) * 64 + L)) * 8;
            *(half8*)(Vf + fo) = sh;
        } else if (local == 4 && w < 4 && kg == 0) {
            const int nt = w;
            half8 sh = {0, 0, 0, 0, 0, 0, 0, 0};
            sh[0] = (_Float16)V_lds[0][nt * 16 + m];   // j == 128
            const size_t fo = ((size_t)((b * 25 + 4 * 5 + nt) * 64 + L)) * 8;
            *(half8*)(Vf + fo) = sh;
        }
    }
}

// ---------------------------------------------------------------------------
// attn: 32 queries/block. grid 256 (b = blk>>7), block 512 (8 waves).
// ROUND-11: every wave computes its own den (ones-plane MFMA, +10 MFMAs
// hidden in the dual accumulate-chain ILP) and broadcasts it within the
// 16-lane group via __shfl(dacc, L&48) — deletes the final __syncthreads,
// den_lds, and the den-wave imbalance.
// Phase 1: wave parity = qt; tile table covers the 18-tile S band.
// Phase 2: wave = (mt = w>>2) x (nt = w&3).
// ---------------------------------------------------------------------------
__global__ __launch_bounds__(512) void attn_kernel(
    const _Float16* __restrict__ Qhi, const _Float16* __restrict__ Qlo,
    const _Float16* __restrict__ Khi, const _Float16* __restrict__ Vf,
    const float* __restrict__ Vs, float* __restrict__ out)
{
    __shared__ __align__(16) _Float16 wt_hi[32 * 168];
    __shared__ __align__(16) _Float16 wt_lo[32 * 168];

    const int tid = threadIdx.x;
    const int L = tid & 63;
    const int w = tid >> 6;              // 0..7
    const int m = L & 15, kg = L >> 4;
    const int b = blockIdx.x >> 7;
    const int n0 = (blockIdx.x & 127) * 32;
    const int qt = w & 1;                // phase-1 q-half
    const int mt = w >> 2;               // phase-2 output q-half
    const int nt = w & 3;                // phase-2 output dim tile

    // ---- upfront load issuance (all independent) ----
    const float vs = Vs[b * HD + nt * 16 + m];         // epilogue const

    const _Float16* qp  = Qhi + ((size_t)(b * NN + n0 + qt * 16 + m)) * HD + kg * 8;
    const _Float16* qp2 = Qlo + ((size_t)(b * NN + n0 + qt * 16 + m)) * HD + kg * 8;
    const half8 qhi0 = *(const half8*)(qp);
    const half8 qhi1 = *(const half8*)(qp + 32);
    const half8 qlo0 = *(const half8*)(qp2);
    const half8 qlo1 = *(const half8*)(qp2 + 32);

    // tile table: even w (qt0) covers kt {0..8}, odd w (qt1) kt {1..9}.
    // i = w>>1: f = {1,2,0,3}[i]; kts = f+qt, f+qt+4, (i==2: f+qt+8).
    const int i4 = w >> 1;
    const int f = (i4 == 0) ? 1 : (i4 == 1) ? 2 : (i4 == 2) ? 0 : 3;
    int kts[3]; int nkt;
    kts[0] = f + qt; kts[1] = f + qt + 4; kts[2] = f + qt + 8;
    nkt = (i4 == 2) ? 3 : 2;

    const _Float16* KB = Khi + (size_t)b * KROWS * HD;
    half8 kh0[3], kh1[3];
#pragma unroll
    for (int i = 0; i < 3; ++i) {
        if (i < nkt) {                   // wave-uniform branch
            const _Float16* kp = KB + (size_t)(n0 + kts[i] * 16 + m) * HD + kg * 8;
            kh0[i] = *(const half8*)(kp);
            kh1[i] = *(const half8*)(kp + 32);
        }
    }

    half8 vhi[5], vh4[5];
#pragma unroll
    for (int jt = 0; jt < 5; ++jt) {
        const size_t fo = ((size_t)((b * 25 + jt * 5 + nt) * 64 + L)) * 8;
        vhi[jt] = *(const half8*)(Vf + fo);
        const size_t fo4 = ((size_t)((b * 25 + jt * 5 + 4) * 64 + L)) * 8;
        vh4[jt] = *(const half8*)(Vf + fo4);
    }

    // zero only the j in [129,161) strip (cols >=160 are never read by
    // phase 2; j<129 is fully written by phase 1). Disjoint from phase-1
    // writes -> no barrier needed before phase 1.
    for (int t = tid; t < 2048; t += 512) {
        const int bufsel = t >= 1024;
        const int idx = t & 1023;
        const int q = idx >> 5;
        const int j = 129 + (idx & 31);
        (bufsel ? wt_lo : wt_hi)[q * 168 + j] = (_Float16)0.f;
    }

    // ---- phase 1 ----
#pragma unroll
    for (int i = 0; i < 3; ++i) {
        if (i < nkt) {
            f32x4 acc = (f32x4){0.f, 0.f, 0.f, 0.f};
            acc = MFMA16(qhi0, kh0[i], acc);
            acc = MFMA16(qhi1, kh1[i], acc);
            acc = MFMA16(qlo0, kh0[i], acc);
            acc = MFMA16(qlo1, kh1[i], acc);
            const int l = kts[i] * 16 + m;
#pragma unroll
            for (int r = 0; r < 4; ++r) {
                const int q = qt * 16 + kg * 4 + r;
                const int j = l - q;
                if (j >= 0 && j < 129) {
                    const float wval = (__expf(acc[r]) - 1.0f) * WSCALE;
                    _Float16 hh, ll; f16_split(wval, hh, ll);
                    wt_hi[q * 168 + j] = hh;
                    wt_lo[q * 168 + j] = ll;
                }
            }
        }
    }
    __syncthreads();

    // ---- phase 2 (all waves: output + own den) ----
    f32x4 oacc = (f32x4){0.f, 0.f, 0.f, 0.f};
    f32x4 dacc = (f32x4){0.f, 0.f, 0.f, 0.f};
#pragma unroll
    for (int jt = 0; jt < 5; ++jt) {
        const half8 whi = *(const half8*)(wt_hi + (mt * 16 + m) * 168 + jt * 32 + kg * 8);
        const half8 wlo = *(const half8*)(wt_lo + (mt * 16 + m) * 168 + jt * 32 + kg * 8);
        oacc = MFMA16(whi, vhi[jt], oacc);
        oacc = MFMA16(wlo, vhi[jt], oacc);
        dacc = MFMA16(whi, vh4[jt], dacc);
        dacc = MFMA16(wlo, vh4[jt], dacc);
    }

    // den lives in lanes m==0 (col 0 of the ones-plane product);
    // broadcast within each 16-lane group. No barrier needed.
    float den[4];
#pragma unroll
    for (int r = 0; r < 4; ++r)
        den[r] = __shfl(dacc[r], L & 48, 64);

    // ---- epilogue (unscale: num = 256*oacc, den = 4096 + 256*den) ----
    {
#pragma unroll
        for (int r = 0; r < 4; ++r) {
            const int q = mt * 16 + kg * 4 + r;
            const float val = (vs + 256.0f * oacc[r])
                            / (4096.f + 256.0f * den[r]);
            out[((size_t)(b * NN + n0 + q)) * HD + nt * 16 + m] = val;
        }
    }
}

// ---------------------------------------------------------------------------
extern "C" void kernel_launch(void* const* d_in, const int* in_sizes, int n_in,
                              void* d_out, int out_size, void* d_ws, size_t ws_size,
                              hipStream_t stream)
{
    const float* x  = (const float*)d_in[0];
    const float* Wq = (const float*)d_in[1];
    const float* bq = (const float*)d_in[2];
    const float* Wk = (const float*)d_in[3];
    const float* bk = (const float*)d_in[4];
    const float* Wv = (const float*)d_in[5];
    const float* bv = (const float*)d_in[6];
    float* out = (float*)d_out;

    char* ws = (char*)d_ws;
    float*     Vs  = (float*)(ws + 0);              //      512 B
    _Float16*  Khi = (_Float16*)(ws + 512);         // 1097728 B
    _Float16*  Qhi = (_Float16*)(ws + 1098240);     // 1048576 B
    _Float16*  Qlo = (_Float16*)(ws + 2146816);     // 1048576 B
    _Float16*  Wf  = (_Float16*)(ws + 3195392);     //  196608 B
    _Float16*  Vf  = (_Float16*)(ws + 3392000);     //   51200 B

    wprep_kernel<<<192, 64, 0, stream>>>(Wq, Wk, Wv, Wf, Khi, Vf, Vs);
    proj_kernel<<<256, 1024, 0, stream>>>(x, Wf, bq, bk, bv,
                                          Qhi, Qlo, Khi, Vf, Vs);
    attn_kernel<<<256, 512, 0, stream>>>(Qhi, Qlo, Khi, Vf, Vs, out);
}